// Round 7
// baseline (432.917 us; speedup 1.0000x reference)
//
#include <hip/hip_runtime.h>

#define N_ROWS 65536
#define DIM    256
#define KCODES 1024

typedef _Float16 h8 __attribute__((ext_vector_type(8)));
typedef _Float16 h4 __attribute__((ext_vector_type(4)));
typedef float    f4 __attribute__((ext_vector_type(4)));

// ---------------------------------------------------------------------------
// Kernel 1a: c_sq[k] = sum_d codebook[k][d]^2 (fp32). One wave per code.
// ---------------------------------------------------------------------------
__global__ __launch_bounds__(64) void prep_csq(const float* __restrict__ cb,
                                               float* __restrict__ csq) {
    const int k = blockIdx.x;
    const int l = threadIdx.x;
    float4 v = reinterpret_cast<const float4*>(cb)[k * 64 + l];
    float s = v.x * v.x + v.y * v.y + v.z * v.z + v.w * v.w;
#pragma unroll
    for (int m = 32; m >= 1; m >>= 1) s += __shfl_xor(s, m, 64);
    if (l == 0) csq[k] = s;
}

// ---------------------------------------------------------------------------
// Kernel 1b: pack codebook into MFMA-B-fragment order, f16 hi/lo.
// packB[((G*8+dc)*8 + j)*512 + lane*8 + e], j = n*2 + (0:hi,1:lo):
// lane(lm=l&15, lk=l>>4) holds B[code=G*64+n*16+lm][d=dc*32+lk*8+e].
// ---------------------------------------------------------------------------
__global__ __launch_bounds__(64) void prep_pack(const float* __restrict__ cb,
                                                _Float16* __restrict__ packB) {
    const int blk = blockIdx.x;        // G*8 + dc  (128 blocks)
    const int G = blk >> 3, dc = blk & 7;
    const int l = threadIdx.x, lm = l & 15, lk = l >> 4;
#pragma unroll
    for (int j = 0; j < 8; ++j) {
        const int n = j >> 1, h = j & 1;
        const int code = G * 64 + n * 16 + lm;
        h8 v;
#pragma unroll
        for (int e = 0; e < 8; ++e) {
            const int d = dc * 32 + lk * 8 + e;
            float val = cb[code * 256 + d];
            _Float16 hi = (_Float16)val;
            v[e] = h ? (_Float16)(val - (float)hi) : hi;
        }
        *reinterpret_cast<h8*>(&packB[((blk * 8 + j) << 9) + (l << 3)]) = v;
    }
}

// ---------------------------------------------------------------------------
// Kernel 2: MFMA distance GEMM + fused argmin. 512 thr (8 waves, 2 wr x 4 wcq).
// A (128 rows, f16 hi/lo, XOR-swizzled) resident in LDS; B streamed from
// packB into registers (2-deep prefetch). NO barriers in the main loop.
// dist_rel = csq[code] - 2*dot  (z_sq dropped: constant per row).
// waves_per_eu(2,2): exactly-2-waves/SIMD contract -> 256-VGPR budget, no
// spill (round-6 allocator chose 128 and spilled ~170MB of scratch).
// ---------------------------------------------------------------------------
__global__ __launch_bounds__(512)
__attribute__((amdgpu_waves_per_eu(2, 2))) void vq_gemm(
    const float* __restrict__ z, const _Float16* __restrict__ packB,
    const float* __restrict__ csq_g,
    float* __restrict__ out_idx, int* __restrict__ idx_ws) {
    __shared__ _Float16 Ahi[128 * 256];   // 64 KB, swizzled
    __shared__ _Float16 Alo[128 * 256];   // 64 KB, swizzled
    __shared__ float csq_s[KCODES];       //  4 KB
    __shared__ float red_val[128 * 4];    //  2 KB
    __shared__ int   red_idx[128 * 4];    //  2 KB   -> 136 KB total

    const int t = threadIdx.x;
    const int row0 = blockIdx.x << 7;     // 128 rows per block
    const int wave = t >> 6;
    const int wr  = wave >> 2;            // 0..1 : row half (64 rows)
    const int wcq = wave & 3;             // 0..3 : code-group slot
    const int lane = t & 63;
    const int lm = lane & 15;
    const int lk = lane >> 4;

    csq_s[t]       = csq_g[t];
    csq_s[t + 512] = csq_g[t + 512];

    // ---- Stage A: z rows -> f16 hi/lo in LDS, swizzled -------------------
    {
        const float4* z4 = reinterpret_cast<const float4*>(z) + (size_t)row0 * 64;
#pragma unroll
        for (int i = 0; i < 16; ++i) {
            int f = t + i * 512;          // 8192 float4s total
            int row = f >> 6, k4 = f & 63;
            float4 v = z4[f];
            h4 hv, lv;
            hv[0] = (_Float16)v.x; lv[0] = (_Float16)(v.x - (float)hv[0]);
            hv[1] = (_Float16)v.y; lv[1] = (_Float16)(v.y - (float)hv[1]);
            hv[2] = (_Float16)v.z; lv[2] = (_Float16)(v.z - (float)hv[2]);
            hv[3] = (_Float16)v.w; lv[3] = (_Float16)(v.w - (float)hv[3]);
            int idx = (row * 256 + k4 * 4) ^ ((row & 7) << 3);
            *reinterpret_cast<h4*>(&Ahi[idx]) = hv;
            *reinterpret_cast<h4*>(&Alo[idx]) = lv;
        }
    }
    __syncthreads();

    float bval[4][4];
    int   bidx[4][4];
#pragma unroll
    for (int m = 0; m < 4; ++m)
#pragma unroll
        for (int j = 0; j < 4; ++j) { bval[m][j] = 3.4e38f; bidx[m][j] = 0x7fffffff; }

    const f4 zacc = {0.0f, 0.0f, 0.0f, 0.0f};

    for (int o = 0; o < 4; ++o) {
        const int G = o * 4 + wcq;        // this wave's 64-code group
        const _Float16* bbase = packB + ((size_t)G << 15);

        f4 acc[4][4];
#pragma unroll
        for (int m = 0; m < 4; ++m)
#pragma unroll
            for (int n = 0; n < 4; ++n) acc[m][n] = zacc;

        h8 bcur[8], bnxt[8];
#pragma unroll
        for (int j = 0; j < 8; ++j)
            bcur[j] = *reinterpret_cast<const h8*>(&bbase[(j << 9) + (lane << 3)]);

        for (int dc = 0; dc < 8; ++dc) {
            if (dc < 7) {
                const _Float16* bb = bbase + ((dc + 1) << 12);
#pragma unroll
                for (int j = 0; j < 8; ++j)
                    bnxt[j] = *reinterpret_cast<const h8*>(&bb[(j << 9) + (lane << 3)]);
            }
            h8 ah[4], al[4];
#pragma unroll
            for (int m = 0; m < 4; ++m) {
                int row = wr * 64 + m * 16 + lm;
                int idx = (row * 256 + dc * 32 + lk * 8) ^ ((row & 7) << 3);
                ah[m] = *reinterpret_cast<const h8*>(&Ahi[idx]);
                al[m] = *reinterpret_cast<const h8*>(&Alo[idx]);
            }
#pragma unroll
            for (int m = 0; m < 4; ++m)
#pragma unroll
                for (int n = 0; n < 4; ++n) {
                    acc[m][n] = __builtin_amdgcn_mfma_f32_16x16x32_f16(ah[m], bcur[n * 2 + 0], acc[m][n], 0, 0, 0);
                    acc[m][n] = __builtin_amdgcn_mfma_f32_16x16x32_f16(al[m], bcur[n * 2 + 0], acc[m][n], 0, 0, 0);
                    acc[m][n] = __builtin_amdgcn_mfma_f32_16x16x32_f16(ah[m], bcur[n * 2 + 1], acc[m][n], 0, 0, 0);
                }
#pragma unroll
            for (int j = 0; j < 8; ++j) bcur[j] = bnxt[j];
        }

        // ---- epilogue: dist_rel + running argmin -------------------------
#pragma unroll
        for (int n = 0; n < 4; ++n) {
            int code = o * 256 + wcq * 64 + n * 16 + lm;
            float cs = csq_s[code];
#pragma unroll
            for (int m = 0; m < 4; ++m)
#pragma unroll
                for (int j = 0; j < 4; ++j) {
                    float d = cs - 2.0f * acc[m][n][j];
                    if (d < bval[m][j] || (d == bval[m][j] && code < bidx[m][j])) {
                        bval[m][j] = d;
                        bidx[m][j] = code;
                    }
                }
        }
    }

    // ---- argmin reduce: butterfly over the 16 col-lanes ------------------
#pragma unroll
    for (int s = 1; s <= 8; s <<= 1) {
#pragma unroll
        for (int m = 0; m < 4; ++m)
#pragma unroll
            for (int j = 0; j < 4; ++j) {
                float ov = __shfl_xor(bval[m][j], s, 64);
                int   oi = __shfl_xor(bidx[m][j], s, 64);
                if (ov < bval[m][j] || (ov == bval[m][j] && oi < bidx[m][j])) {
                    bval[m][j] = ov;
                    bidx[m][j] = oi;
                }
            }
    }
    if (lm == 0) {
#pragma unroll
        for (int m = 0; m < 4; ++m)
#pragma unroll
            for (int j = 0; j < 4; ++j) {
                int rl = wr * 64 + m * 16 + lk * 4 + j;
                red_val[rl * 4 + wcq] = bval[m][j];
                red_idx[rl * 4 + wcq] = bidx[m][j];
            }
    }
    __syncthreads();
    if (t < 128) {  // cross-wave (code-group) reduce
        float bv = red_val[t * 4];
        int   bi = red_idx[t * 4];
#pragma unroll
        for (int w = 1; w < 4; ++w) {
            float v = red_val[t * 4 + w];
            int   i2 = red_idx[t * 4 + w];
            if (v < bv || (v == bv && i2 < bi)) { bv = v; bi = i2; }
        }
        out_idx[row0 + t] = (float)bi;
        idx_ws[row0 + t] = bi;
    }
}

// ---------------------------------------------------------------------------
// Kernel 3: per-block histogram of indices (int, LDS-reduced).
// ---------------------------------------------------------------------------
__global__ __launch_bounds__(256) void hist_kernel(const int* __restrict__ idx_ws,
                                                   int* __restrict__ counts_i) {
    __shared__ int h[KCODES];
    const int t = threadIdx.x;
#pragma unroll
    for (int i = 0; i < 4; ++i) h[t + i * 256] = 0;
    __syncthreads();
    atomicAdd(&h[idx_ws[blockIdx.x * 256 + t]], 1);
    __syncthreads();
#pragma unroll
    for (int i = 0; i < 4; ++i) {
        int c = h[t + i * 256];
        if (c) atomicAdd(&counts_i[t + i * 256], c);
    }
}

// ---------------------------------------------------------------------------
// Kernel 4: exclusive prefix scan of counts (single block, 1024 threads).
// ---------------------------------------------------------------------------
__global__ __launch_bounds__(1024) void scan_kernel(const int* __restrict__ counts_i,
                                                    int* __restrict__ offsets,
                                                    int* __restrict__ cursor) {
    __shared__ int a[KCODES], b[KCODES];
    const int t = threadIdx.x;
    int cnt = counts_i[t];
    a[t] = cnt;
    __syncthreads();
    int* src = a; int* dst = b;
    for (int s = 1; s < 1024; s <<= 1) {
        dst[t] = (t >= s) ? (src[t - s] + src[t]) : src[t];
        __syncthreads();
        int* tmp = src; src = dst; dst = tmp;
    }
    int excl = src[t] - cnt;
    offsets[t] = excl;
    cursor[t] = excl;
}

// ---------------------------------------------------------------------------
// Kernel 5: bucket placement — perm lists row ids grouped by code.
// ---------------------------------------------------------------------------
__global__ __launch_bounds__(256) void place_kernel(const int* __restrict__ idx_ws,
                                                    int* __restrict__ cursor,
                                                    int* __restrict__ perm) {
    const int r = blockIdx.x * 256 + threadIdx.x;
    const int c = idx_ws[r];
    const int pos = atomicAdd(&cursor[c], 1);
    perm[pos] = r;
}

// ---------------------------------------------------------------------------
// Kernel 6a: sliced segmented reduction over the sorted perm list.
// 2048 blocks x 32 perm entries; thread t owns dim t. Codes are block-uniform
// (LDS), so the flush branch is non-divergent; atomicAdd only at segment
// boundaries.
// ---------------------------------------------------------------------------
__global__ __launch_bounds__(256) void segsum_partial(
    const float* __restrict__ z, const int* __restrict__ perm,
    const int* __restrict__ idx_ws, float* __restrict__ sums) {
    __shared__ int srow[32];
    __shared__ int scode[32];
    const int t = threadIdx.x;
    const int base = blockIdx.x << 5;
    if (t < 32) {
        int r = perm[base + t];
        srow[t] = r;
        scode[t] = idx_ws[r];
    }
    __syncthreads();
    float s = z[(size_t)srow[0] * 256 + t];
    int cur = scode[0];
#pragma unroll 8
    for (int i = 1; i < 32; ++i) {
        int c = scode[i];
        float v = z[(size_t)srow[i] * 256 + t];
        if (c != cur) {                    // block-uniform branch
            atomicAdd(&sums[cur * 256 + t], s);
            s = v; cur = c;
        } else {
            s += v;
        }
    }
    atomicAdd(&sums[cur * 256 + t], s);
}

// ---------------------------------------------------------------------------
// Kernel 6b: EMA update + codebook normalization.
// ---------------------------------------------------------------------------
__global__ __launch_bounds__(256) void ema_kernel(
    const float* __restrict__ cluster_size, const float* __restrict__ embed_avg,
    const float* __restrict__ sums, const int* __restrict__ counts_i,
    float* __restrict__ out_cb, float* __restrict__ out_cs, float* __restrict__ out_ea) {
    const int k = blockIdx.x, d = threadIdx.x;
    const float ncs = cluster_size[k] * 0.99f + (float)counts_i[k] * 0.01f;
    const int o = k * 256 + d;
    const float nea = embed_avg[o] * 0.99f + sums[o] * 0.01f;
    out_ea[o] = nea;
    out_cb[o] = nea / (ncs + 1e-5f);
    if (d == 0) out_cs[k] = ncs;
}

// ---------------------------------------------------------------------------
// Kernel 7: STE / z_q gather, pure float4 streaming.
// ---------------------------------------------------------------------------
__global__ __launch_bounds__(256) void ste_kernel(const float* __restrict__ z,
                                                  const float* __restrict__ cb,
                                                  const int* __restrict__ idx_ws,
                                                  float* __restrict__ out_zq) {
    __shared__ int sidx[32];
    const int t = threadIdx.x;
    const int r0 = blockIdx.x << 5;       // 32 rows per block
    if (t < 32) sidx[t] = idx_ws[r0 + t];
    __syncthreads();
    const int rs = t >> 6;                // 0..3 row-sub
    const int c4 = t & 63;                // float4 column
#pragma unroll 1
    for (int it = 0; it < 8; ++it) {
        int r = it * 4 + rs;
        int bk = sidx[r];
        float4 zv = reinterpret_cast<const float4*>(z)[(size_t)(r0 + r) * 64 + c4];
        float4 cv = reinterpret_cast<const float4*>(cb)[bk * 64 + c4];
        float4 ov;
        ov.x = zv.x + (cv.x - zv.x);      // exact reference STE arithmetic
        ov.y = zv.y + (cv.y - zv.y);
        ov.z = zv.z + (cv.z - zv.z);
        ov.w = zv.w + (cv.w - zv.w);
        reinterpret_cast<float4*>(out_zq)[(size_t)(r0 + r) * 64 + c4] = ov;
    }
}

// ---------------------------------------------------------------------------
extern "C" void kernel_launch(void* const* d_in, const int* in_sizes, int n_in,
                              void* d_out, int out_size, void* d_ws, size_t ws_size,
                              hipStream_t stream) {
    const float* z            = (const float*)d_in[0];
    const float* cb           = (const float*)d_in[1];
    const float* cluster_size = (const float*)d_in[2];
    const float* embed_avg    = (const float*)d_in[3];

    float* out_zq  = (float*)d_out;                      // 65536*256
    float* out_idx = out_zq + (size_t)N_ROWS * DIM;      // 65536
    float* out_cb  = out_idx + N_ROWS;                   // 1024*256
    float* out_cs  = out_cb + (size_t)KCODES * DIM;      // 1024
    float* out_ea  = out_cs + KCODES;                    // 1024*256

    // ws: packB 1MB | csq 4KB | idx 256KB | counts_i 4KB | offsets 4KB |
    //     cursor 4KB | perm 256KB | sums 1MB   (~2.6 MB)
    char* w = (char*)d_ws;
    _Float16* packB = (_Float16*)w;   w += (size_t)KCODES * DIM * 2 * 2;
    float* csq      = (float*)w;      w += (size_t)KCODES * 4;
    int* idx_ws     = (int*)w;        w += (size_t)N_ROWS * 4;
    int* counts_i   = (int*)w;        w += (size_t)KCODES * 4;
    int* offsets    = (int*)w;        w += (size_t)KCODES * 4;
    int* cursor     = (int*)w;        w += (size_t)KCODES * 4;
    int* perm       = (int*)w;        w += (size_t)N_ROWS * 4;
    float* sums     = (float*)w;

    hipMemsetAsync(counts_i, 0, KCODES * sizeof(int), stream);
    hipMemsetAsync(sums, 0, (size_t)KCODES * DIM * sizeof(float), stream);
    prep_csq<<<KCODES, 64, 0, stream>>>(cb, csq);
    prep_pack<<<128, 64, 0, stream>>>(cb, packB);
    vq_gemm<<<N_ROWS / 128, 512, 0, stream>>>(z, packB, csq, out_idx, idx_ws);
    hist_kernel<<<N_ROWS / 256, 256, 0, stream>>>(idx_ws, counts_i);
    scan_kernel<<<1, 1024, 0, stream>>>(counts_i, offsets, cursor);
    place_kernel<<<N_ROWS / 256, 256, 0, stream>>>(idx_ws, cursor, perm);
    segsum_partial<<<N_ROWS / 32, 256, 0, stream>>>(z, perm, idx_ws, sums);
    ema_kernel<<<KCODES, 256, 0, stream>>>(cluster_size, embed_avg, sums, counts_i,
                                           out_cb, out_cs, out_ea);
    ste_kernel<<<N_ROWS / 32, 256, 0, stream>>>(z, cb, idx_ws, out_zq);
}

// Round 8
// 349.393 us; speedup vs baseline: 1.2391x; 1.2391x over previous
//
#include <hip/hip_runtime.h>

#define N_ROWS 65536
#define DIM    256
#define KCODES 1024

typedef _Float16 h8 __attribute__((ext_vector_type(8)));
typedef _Float16 h4 __attribute__((ext_vector_type(4)));
typedef float    f4 __attribute__((ext_vector_type(4)));

// ---------------------------------------------------------------------------
// Kernel 1a: c_sq[k] = sum_d codebook[k][d]^2 (fp32). One wave per code.
// ---------------------------------------------------------------------------
__global__ __launch_bounds__(64) void prep_csq(const float* __restrict__ cb,
                                               float* __restrict__ csq) {
    const int k = blockIdx.x;
    const int l = threadIdx.x;
    float4 v = reinterpret_cast<const float4*>(cb)[k * 64 + l];
    float s = v.x * v.x + v.y * v.y + v.z * v.z + v.w * v.w;
#pragma unroll
    for (int m = 32; m >= 1; m >>= 1) s += __shfl_xor(s, m, 64);
    if (l == 0) csq[k] = s;
}

// ---------------------------------------------------------------------------
// Kernel 1b: pack codebook into MFMA-B-fragment order, f16 hi/lo.
// packB[((G*8+dc)*8 + j)*512 + lane*8 + e], j = n*2 + (0:hi,1:lo):
// lane(lm=l&15, lk=l>>4) holds B[code=G*64+n*16+lm][d=dc*32+lk*8+e].
// ---------------------------------------------------------------------------
__global__ __launch_bounds__(64) void prep_pack(const float* __restrict__ cb,
                                                _Float16* __restrict__ packB) {
    const int blk = blockIdx.x;        // G*8 + dc  (128 blocks)
    const int G = blk >> 3, dc = blk & 7;
    const int l = threadIdx.x, lm = l & 15, lk = l >> 4;
#pragma unroll
    for (int j = 0; j < 8; ++j) {
        const int n = j >> 1, h = j & 1;
        const int code = G * 64 + n * 16 + lm;
        h8 v;
#pragma unroll
        for (int e = 0; e < 8; ++e) {
            const int d = dc * 32 + lk * 8 + e;
            float val = cb[code * 256 + d];
            _Float16 hi = (_Float16)val;
            v[e] = h ? (_Float16)(val - (float)hi) : hi;
        }
        *reinterpret_cast<h8*>(&packB[((blk * 8 + j) << 9) + (l << 3)]) = v;
    }
}

// ---------------------------------------------------------------------------
// Kernel 2: MFMA distance GEMM + fused argmin. 512 thr = 8 waves arranged as
// 4 row-tiles (wr, 32 rows) x 2 code-groups (wc, 64 codes). o-loop covers
// 1024 codes in 8 passes of 128. Live set ~112 VGPR (acc 32 + B 32 + A 16 +
// argmin 16 + addr) -> fits the 128-reg allocation WITHOUT spill (rounds 6/7
// spilled ~170MB scratch at the 64x64 wave tile). No main-loop barriers.
// dist_rel = csq[code] - 2*dot  (z_sq dropped: constant per row).
// ---------------------------------------------------------------------------
#define MF(A, B, C) C = __builtin_amdgcn_mfma_f32_16x16x32_f16(A, B, C, 0, 0, 0)

__global__ __launch_bounds__(512, 2) void vq_gemm(
    const float* __restrict__ z, const _Float16* __restrict__ packB,
    const float* __restrict__ csq_g,
    float* __restrict__ out_idx, int* __restrict__ idx_ws) {
    __shared__ _Float16 Ahi[128 * 256];   // 64 KB, swizzled
    __shared__ _Float16 Alo[128 * 256];   // 64 KB, swizzled
    __shared__ float csq_s[KCODES];       //  4 KB
    __shared__ float red_val[128 * 2];    //  1 KB
    __shared__ int   red_idx[128 * 2];    //  1 KB   -> 134 KB total

    const int t = threadIdx.x;
    const int row0 = blockIdx.x << 7;     // 128 rows per block
    const int wave = t >> 6;
    const int wr = wave >> 1;             // 0..3 : 32-row tile
    const int wc = wave & 1;              // 0..1 : 64-code group slot
    const int lane = t & 63;
    const int lm = lane & 15;
    const int lk = lane >> 4;

    csq_s[t]       = csq_g[t];
    csq_s[t + 512] = csq_g[t + 512];

    // ---- Stage A: z rows -> f16 hi/lo in LDS, swizzled -------------------
    {
        const float4* z4 = reinterpret_cast<const float4*>(z) + (size_t)row0 * 64;
#pragma unroll
        for (int i = 0; i < 16; ++i) {
            int f = t + i * 512;          // 8192 float4s total
            int row = f >> 6, k4 = f & 63;
            float4 v = z4[f];
            h4 hv, lv;
            hv[0] = (_Float16)v.x; lv[0] = (_Float16)(v.x - (float)hv[0]);
            hv[1] = (_Float16)v.y; lv[1] = (_Float16)(v.y - (float)hv[1]);
            hv[2] = (_Float16)v.z; lv[2] = (_Float16)(v.z - (float)hv[2]);
            hv[3] = (_Float16)v.w; lv[3] = (_Float16)(v.w - (float)hv[3]);
            int idx = (row * 256 + k4 * 4) ^ ((row & 7) << 3);
            *reinterpret_cast<h4*>(&Ahi[idx]) = hv;
            *reinterpret_cast<h4*>(&Alo[idx]) = lv;
        }
    }
    __syncthreads();

    float bval[2][4];
    int   bidx[2][4];
#pragma unroll
    for (int m = 0; m < 2; ++m)
#pragma unroll
        for (int j = 0; j < 4; ++j) { bval[m][j] = 3.4e38f; bidx[m][j] = 0x7fffffff; }

    const f4 zacc = {0.0f, 0.0f, 0.0f, 0.0f};

    // A-row addressing (dc-invariant parts)
    const int r0_ = wr * 32 + lm;
    const int r1_ = r0_ + 16;
    const int sw  = (r0_ & 7) << 3;       // same for r1_ (+16 keeps row&7)
    const int aoff0 = r0_ * 256 + lk * 8;
    const int aoff1 = r1_ * 256 + lk * 8;

    for (int o = 0; o < 8; ++o) {
        const int G = o * 2 + wc;         // this wave's 64-code group
        const h8* bb8 = reinterpret_cast<const h8*>(packB) + ((size_t)G << 12) + lane;

        f4 acc[2][4];
#pragma unroll
        for (int m = 0; m < 2; ++m)
#pragma unroll
            for (int n = 0; n < 4; ++n) acc[m][n] = zacc;

        for (int dc = 0; dc < 8; ++dc) {
            // B: 8 named h8 loads, constant offsets (L2-resident packB)
            const h8* bp = bb8 + (dc << 9);
            h8 b0 = bp[0];            // n=0 hi
            h8 b1 = bp[64];           // n=0 lo
            h8 b2 = bp[128];          // n=1 hi
            h8 b3 = bp[192];          // n=1 lo
            h8 b4 = bp[256];          // n=2 hi
            h8 b5 = bp[320];          // n=2 lo
            h8 b6 = bp[384];          // n=3 hi
            h8 b7 = bp[448];          // n=3 lo

            const int i0 = (aoff0 + dc * 32) ^ sw;
            const int i1 = (aoff1 + dc * 32) ^ sw;
            h8 ah0 = *reinterpret_cast<const h8*>(&Ahi[i0]);
            h8 al0 = *reinterpret_cast<const h8*>(&Alo[i0]);
            h8 ah1 = *reinterpret_cast<const h8*>(&Ahi[i1]);
            h8 al1 = *reinterpret_cast<const h8*>(&Alo[i1]);

            MF(ah0, b0, acc[0][0]); MF(al0, b0, acc[0][0]); MF(ah0, b1, acc[0][0]);
            MF(ah1, b0, acc[1][0]); MF(al1, b0, acc[1][0]); MF(ah1, b1, acc[1][0]);
            MF(ah0, b2, acc[0][1]); MF(al0, b2, acc[0][1]); MF(ah0, b3, acc[0][1]);
            MF(ah1, b2, acc[1][1]); MF(al1, b2, acc[1][1]); MF(ah1, b3, acc[1][1]);
            MF(ah0, b4, acc[0][2]); MF(al0, b4, acc[0][2]); MF(ah0, b5, acc[0][2]);
            MF(ah1, b4, acc[1][2]); MF(al1, b4, acc[1][2]); MF(ah1, b5, acc[1][2]);
            MF(ah0, b6, acc[0][3]); MF(al0, b6, acc[0][3]); MF(ah0, b7, acc[0][3]);
            MF(ah1, b6, acc[1][3]); MF(al1, b6, acc[1][3]); MF(ah1, b7, acc[1][3]);
        }

        // ---- epilogue: dist_rel + running argmin -------------------------
#pragma unroll
        for (int n = 0; n < 4; ++n) {
            int code = G * 64 + n * 16 + lm;
            float cs = csq_s[code];
#pragma unroll
            for (int m = 0; m < 2; ++m)
#pragma unroll
                for (int j = 0; j < 4; ++j) {
                    float d = cs - 2.0f * acc[m][n][j];
                    if (d < bval[m][j] || (d == bval[m][j] && code < bidx[m][j])) {
                        bval[m][j] = d;
                        bidx[m][j] = code;
                    }
                }
        }
    }

    // ---- argmin reduce: butterfly over the 16 col-lanes ------------------
#pragma unroll
    for (int s = 1; s <= 8; s <<= 1) {
#pragma unroll
        for (int m = 0; m < 2; ++m)
#pragma unroll
            for (int j = 0; j < 4; ++j) {
                float ov = __shfl_xor(bval[m][j], s, 64);
                int   oi = __shfl_xor(bidx[m][j], s, 64);
                if (ov < bval[m][j] || (ov == bval[m][j] && oi < bidx[m][j])) {
                    bval[m][j] = ov;
                    bidx[m][j] = oi;
                }
            }
    }
    if (lm == 0) {
#pragma unroll
        for (int m = 0; m < 2; ++m)
#pragma unroll
            for (int j = 0; j < 4; ++j) {
                int rl = wr * 32 + m * 16 + lk * 4 + j;
                red_val[rl * 2 + wc] = bval[m][j];
                red_idx[rl * 2 + wc] = bidx[m][j];
            }
    }
    __syncthreads();
    if (t < 128) {  // cross-wave (code-group) reduce
        float bv = red_val[t * 2];
        int   bi = red_idx[t * 2];
        float v = red_val[t * 2 + 1];
        int   i2 = red_idx[t * 2 + 1];
        if (v < bv || (v == bv && i2 < bi)) { bv = v; bi = i2; }
        out_idx[row0 + t] = (float)bi;
        idx_ws[row0 + t] = bi;
    }
}

// ---------------------------------------------------------------------------
// Kernel 3: per-block histogram of indices (int, LDS-reduced).
// ---------------------------------------------------------------------------
__global__ __launch_bounds__(256) void hist_kernel(const int* __restrict__ idx_ws,
                                                   int* __restrict__ counts_i) {
    __shared__ int h[KCODES];
    const int t = threadIdx.x;
#pragma unroll
    for (int i = 0; i < 4; ++i) h[t + i * 256] = 0;
    __syncthreads();
    atomicAdd(&h[idx_ws[blockIdx.x * 256 + t]], 1);
    __syncthreads();
#pragma unroll
    for (int i = 0; i < 4; ++i) {
        int c = h[t + i * 256];
        if (c) atomicAdd(&counts_i[t + i * 256], c);
    }
}

// ---------------------------------------------------------------------------
// Kernel 4: exclusive prefix scan of counts (single block, 1024 threads).
// ---------------------------------------------------------------------------
__global__ __launch_bounds__(1024) void scan_kernel(const int* __restrict__ counts_i,
                                                    int* __restrict__ offsets,
                                                    int* __restrict__ cursor) {
    __shared__ int a[KCODES], b[KCODES];
    const int t = threadIdx.x;
    int cnt = counts_i[t];
    a[t] = cnt;
    __syncthreads();
    int* src = a; int* dst = b;
    for (int s = 1; s < 1024; s <<= 1) {
        dst[t] = (t >= s) ? (src[t - s] + src[t]) : src[t];
        __syncthreads();
        int* tmp = src; src = dst; dst = tmp;
    }
    int excl = src[t] - cnt;
    offsets[t] = excl;
    cursor[t] = excl;
}

// ---------------------------------------------------------------------------
// Kernel 5: bucket placement — perm lists row ids grouped by code.
// ---------------------------------------------------------------------------
__global__ __launch_bounds__(256) void place_kernel(const int* __restrict__ idx_ws,
                                                    int* __restrict__ cursor,
                                                    int* __restrict__ perm) {
    const int r = blockIdx.x * 256 + threadIdx.x;
    const int c = idx_ws[r];
    const int pos = atomicAdd(&cursor[c], 1);
    perm[pos] = r;
}

// ---------------------------------------------------------------------------
// Kernel 6a: sliced segmented reduction over the sorted perm list.
// 2048 blocks x 32 perm entries; thread t owns dim t. Codes are block-uniform
// (LDS), so the flush branch is non-divergent; atomicAdd only at segment
// boundaries.
// ---------------------------------------------------------------------------
__global__ __launch_bounds__(256) void segsum_partial(
    const float* __restrict__ z, const int* __restrict__ perm,
    const int* __restrict__ idx_ws, float* __restrict__ sums) {
    __shared__ int srow[32];
    __shared__ int scode[32];
    const int t = threadIdx.x;
    const int base = blockIdx.x << 5;
    if (t < 32) {
        int r = perm[base + t];
        srow[t] = r;
        scode[t] = idx_ws[r];
    }
    __syncthreads();
    float s = z[(size_t)srow[0] * 256 + t];
    int cur = scode[0];
#pragma unroll 8
    for (int i = 1; i < 32; ++i) {
        int c = scode[i];
        float v = z[(size_t)srow[i] * 256 + t];
        if (c != cur) {                    // block-uniform branch
            atomicAdd(&sums[cur * 256 + t], s);
            s = v; cur = c;
        } else {
            s += v;
        }
    }
    atomicAdd(&sums[cur * 256 + t], s);
}

// ---------------------------------------------------------------------------
// Kernel 6b: EMA update + codebook normalization.
// ---------------------------------------------------------------------------
__global__ __launch_bounds__(256) void ema_kernel(
    const float* __restrict__ cluster_size, const float* __restrict__ embed_avg,
    const float* __restrict__ sums, const int* __restrict__ counts_i,
    float* __restrict__ out_cb, float* __restrict__ out_cs, float* __restrict__ out_ea) {
    const int k = blockIdx.x, d = threadIdx.x;
    const float ncs = cluster_size[k] * 0.99f + (float)counts_i[k] * 0.01f;
    const int o = k * 256 + d;
    const float nea = embed_avg[o] * 0.99f + sums[o] * 0.01f;
    out_ea[o] = nea;
    out_cb[o] = nea / (ncs + 1e-5f);
    if (d == 0) out_cs[k] = ncs;
}

// ---------------------------------------------------------------------------
// Kernel 7: STE / z_q gather, pure float4 streaming.
// ---------------------------------------------------------------------------
__global__ __launch_bounds__(256) void ste_kernel(const float* __restrict__ z,
                                                  const float* __restrict__ cb,
                                                  const int* __restrict__ idx_ws,
                                                  float* __restrict__ out_zq) {
    __shared__ int sidx[32];
    const int t = threadIdx.x;
    const int r0 = blockIdx.x << 5;       // 32 rows per block
    if (t < 32) sidx[t] = idx_ws[r0 + t];
    __syncthreads();
    const int rs = t >> 6;                // 0..3 row-sub
    const int c4 = t & 63;                // float4 column
#pragma unroll 1
    for (int it = 0; it < 8; ++it) {
        int r = it * 4 + rs;
        int bk = sidx[r];
        float4 zv = reinterpret_cast<const float4*>(z)[(size_t)(r0 + r) * 64 + c4];
        float4 cv = reinterpret_cast<const float4*>(cb)[bk * 64 + c4];
        float4 ov;
        ov.x = zv.x + (cv.x - zv.x);      // exact reference STE arithmetic
        ov.y = zv.y + (cv.y - zv.y);
        ov.z = zv.z + (cv.z - zv.z);
        ov.w = zv.w + (cv.w - zv.w);
        reinterpret_cast<float4*>(out_zq)[(size_t)(r0 + r) * 64 + c4] = ov;
    }
}

// ---------------------------------------------------------------------------
extern "C" void kernel_launch(void* const* d_in, const int* in_sizes, int n_in,
                              void* d_out, int out_size, void* d_ws, size_t ws_size,
                              hipStream_t stream) {
    const float* z            = (const float*)d_in[0];
    const float* cb           = (const float*)d_in[1];
    const float* cluster_size = (const float*)d_in[2];
    const float* embed_avg    = (const float*)d_in[3];

    float* out_zq  = (float*)d_out;                      // 65536*256
    float* out_idx = out_zq + (size_t)N_ROWS * DIM;      // 65536
    float* out_cb  = out_idx + N_ROWS;                   // 1024*256
    float* out_cs  = out_cb + (size_t)KCODES * DIM;      // 1024
    float* out_ea  = out_cs + KCODES;                    // 1024*256

    // ws: packB 1MB | csq 4KB | idx 256KB | counts_i 4KB | offsets 4KB |
    //     cursor 4KB | perm 256KB | sums 1MB   (~2.6 MB)
    char* w = (char*)d_ws;
    _Float16* packB = (_Float16*)w;   w += (size_t)KCODES * DIM * 2 * 2;
    float* csq      = (float*)w;      w += (size_t)KCODES * 4;
    int* idx_ws     = (int*)w;        w += (size_t)N_ROWS * 4;
    int* counts_i   = (int*)w;        w += (size_t)KCODES * 4;
    int* offsets    = (int*)w;        w += (size_t)KCODES * 4;
    int* cursor     = (int*)w;        w += (size_t)KCODES * 4;
    int* perm       = (int*)w;        w += (size_t)N_ROWS * 4;
    float* sums     = (float*)w;

    hipMemsetAsync(counts_i, 0, KCODES * sizeof(int), stream);
    hipMemsetAsync(sums, 0, (size_t)KCODES * DIM * sizeof(float), stream);
    prep_csq<<<KCODES, 64, 0, stream>>>(cb, csq);
    prep_pack<<<128, 64, 0, stream>>>(cb, packB);
    vq_gemm<<<N_ROWS / 128, 512, 0, stream>>>(z, packB, csq, out_idx, idx_ws);
    hist_kernel<<<N_ROWS / 256, 256, 0, stream>>>(idx_ws, counts_i);
    scan_kernel<<<1, 1024, 0, stream>>>(counts_i, offsets, cursor);
    place_kernel<<<N_ROWS / 256, 256, 0, stream>>>(idx_ws, cursor, perm);
    segsum_partial<<<N_ROWS / 32, 256, 0, stream>>>(z, perm, idx_ws, sums);
    ema_kernel<<<KCODES, 256, 0, stream>>>(cluster_size, embed_avg, sums, counts_i,
                                           out_cb, out_cs, out_ea);
    ste_kernel<<<N_ROWS / 32, 256, 0, stream>>>(z, cb, idx_ws, out_zq);
}